// Round 3
// baseline (1736.185 us; speedup 1.0000x reference)
//
#include <hip/hip_runtime.h>
#include <hip/hip_bf16.h>

// Problem constants
#define Tt   50
#define Dd   64
#define NOUT 100
#define G4   512   // 4*H
#define K0P  200   // padded LDS stride for layer0 A (192 + 8)
#define K1P  264   // padded LDS stride for layer1 A (256 + 8)
#define BM   32    // batch rows per workgroup

typedef __attribute__((ext_vector_type(8))) short  short8;
typedef __attribute__((ext_vector_type(4))) float  floatx4;

__device__ __forceinline__ float fsig(float v)  { return 1.0f / (1.0f + __expf(-v)); }
__device__ __forceinline__ float ftanh_(float v) { return 2.0f / (1.0f + __expf(-2.0f * v)) - 1.0f; }
__device__ __forceinline__ short f2bf(float f) {
    __hip_bfloat16 h = __float2bfloat16(f);
    return *reinterpret_cast<const short*>(&h);
}

// ws layout (bytes):
//  w0f bf16[ 98304] @ 0        (layer0 combined [Wk0;Wr0] 192x512, frag-ordered, nt*6+kt)
//  w1f bf16[131072] @ 196608   (layer1 combined [Wk1;Wr1] 256x512, frag-ordered, nt*8+kt)
//  wdf bf16[  8192] @ 458752   (Wd 128x64, frag-ordered, nt*4+kt)
//  b0f f32[512]     @ 475136
//  b1f f32[512]     @ 477184
//  bdf f32[64]      @ 479232
#define W1F_OFF 196608
#define WDF_OFF 458752
#define B0F_OFF 475136
#define B1F_OFF 477184
#define BDF_OFF 479232

__global__ __launch_bounds__(256) void prep_kernel(
    const float* __restrict__ Wk0, const float* __restrict__ Wr0, const float* __restrict__ b0,
    const float* __restrict__ Wk1, const float* __restrict__ Wr1, const float* __restrict__ b1,
    const float* __restrict__ Wd,  const float* __restrict__ bd,  char* __restrict__ ws)
{
    int idx = blockIdx.x * 256 + threadIdx.x;
    short* w0f = (short*)ws;
    short* w1f = (short*)(ws + W1F_OFF);
    short* wdf = (short*)(ws + WDF_OFF);
    float* b0f = (float*)(ws + B0F_OFF);
    float* b1f = (float*)(ws + B1F_OFF);
    float* bdf = (float*)(ws + BDF_OFF);

    if (idx < 98304) {
        int f = idx >> 9, r = idx & 511;
        int lane = r >> 3, j = r & 7;
        int nt = f / 6, kt = f - nt * 6;
        int k = kt * 32 + (lane >> 4) * 8 + j;
        int col = nt * 16 + (lane & 15);
        w0f[idx] = f2bf((k < Dd) ? Wk0[k * G4 + col] : Wr0[(k - Dd) * G4 + col]);
    } else if (idx < 229376) {
        int i2 = idx - 98304;
        int f = i2 >> 9, r = i2 & 511;
        int lane = r >> 3, j = r & 7;
        int nt = f >> 3, kt = f & 7;
        int k = kt * 32 + (lane >> 4) * 8 + j;
        int col = nt * 16 + (lane & 15);
        w1f[i2] = f2bf((k < 128) ? Wk1[k * G4 + col] : Wr1[(k - 128) * G4 + col]);
    } else if (idx < 237568) {
        int i2 = idx - 229376;
        int f = i2 >> 9, r = i2 & 511;
        int lane = r >> 3, j = r & 7;
        int nt = f >> 2, kt = f & 3;
        int k = kt * 32 + (lane >> 4) * 8 + j;
        int col = nt * 16 + (lane & 15);
        wdf[i2] = f2bf(Wd[k * Dd + col]);
    } else if (idx < 237568 + 1088) {
        int i2 = idx - 237568;
        if (i2 < 512)       b0f[i2]        = b0[i2];
        else if (i2 < 1024) b1f[i2 - 512]  = b1[i2 - 512];
        else                bdf[i2 - 1024] = bd[i2 - 1024];
    }
}

// grid 128, block 512 (8 waves). Wave w owns gate-column n-tiles {w, 8+w, 16+w, 24+w}
// so i/f/g/o for hidden unit hu = 16w + (lane&15) land in the same lane/reg of the
// 4 accumulators -> gates computed entirely in registers, no z LDS exchange.
__global__ __launch_bounds__(512, 2) void lstm_kernel(
    const float* __restrict__ x, const char* __restrict__ ws, float* __restrict__ out)
{
    const short* w0f = (const short*)ws;
    const short* w1f = (const short*)(ws + W1F_OFF);
    const short* wdf = (const short*)(ws + WDF_OFF);
    const float* b0f = (const float*)(ws + B0F_OFF);
    const float* b1f = (const float*)(ws + B1F_OFF);
    const float* bdf = (const float*)(ws + BDF_OFF);

    __shared__ __align__(16) short a0[BM * K0P];  // [row][k]: k<64 x/pred, 64..191 h0
    __shared__ __align__(16) short a1[BM * K1P];  // [row][k]: k<128 h0,    128..255 h1

    const int tid  = threadIdx.x;
    const int w    = tid >> 6;        // wave 0..7
    const int lane = tid & 63;
    const int l15  = lane & 15;
    const int quad = lane >> 4;
    const int row0 = blockIdx.x * BM;

    // init LDS state to zero (h0, h1, x region)
    for (int i = tid; i < BM * K0P; i += 512) a0[i] = 0;
    for (int i = tid; i < BM * K1P; i += 512) a1[i] = 0;
    __syncthreads();

    // per-lane constants
    const int hu = w * 16 + l15;                 // hidden unit handled by this lane
    const float bi0 = b0f[hu], bff0 = b0f[128 + hu], bg0 = b0f[256 + hu], bo0 = b0f[384 + hu];
    const float bi1 = b1f[hu], bff1 = b1f[128 + hu], bg1 = b1f[256 + hu], bo1 = b1f[384 + hu];
    const int dnt = w & 3, dmt = w >> 2;         // dense tile owned by this wave
    const float bdv = bdf[dnt * 16 + l15];

    // per-wave fragment-ordered weight bases (nt = w + 8g)
    const short* w0b = w0f + w * (6 * 512) + lane * 8;   // + g*24576 + kt*512
    const short* w1b = w1f + w * (8 * 512) + lane * 8;   // + g*32768 + kt*512
    const short* wdb = wdf + dnt * (4 * 512) + lane * 8; // + kt*512

    float c0s[2][4] = {{0.f,0.f,0.f,0.f},{0.f,0.f,0.f,0.f}};
    float c1s[2][4] = {{0.f,0.f,0.f,0.f},{0.f,0.f,0.f,0.f}};

    for (int step = 0; step < 149; ++step) {
        if (step < Tt) {
            // stage x[:, step, :] -> a0 cols 0..63 (fp32 -> bf16, coalesced 256B per row)
            int colx = tid & 63, rg = tid >> 6;
            #pragma unroll
            for (int kk = 0; kk < 4; ++kk) {
                int r = rg + 8 * kk;
                a0[r * K0P + colx] = f2bf(x[(size_t)(row0 + r) * (Tt * Dd) + step * Dd + colx]);
            }
        }
        __syncthreads();  // b1: a0 (x or pred, h0) ready

        // ---------- layer 0: z0 = [x;h0] @ [Wk0;Wr0] ----------
        short8 af0[2][6];
        #pragma unroll
        for (int mt = 0; mt < 2; ++mt)
            #pragma unroll
            for (int kt = 0; kt < 6; ++kt)
                af0[mt][kt] = *(const short8*)&a0[(mt * 16 + l15) * K0P + kt * 32 + quad * 8];

        floatx4 acc[4][2];
        #pragma unroll
        for (int g = 0; g < 4; ++g)
            #pragma unroll
            for (int mt = 0; mt < 2; ++mt)
                acc[g][mt] = (floatx4){0.f, 0.f, 0.f, 0.f};

        #pragma unroll
        for (int g = 0; g < 4; ++g) {
            #pragma unroll
            for (int kt = 0; kt < 6; ++kt) {
                short8 bfr = *(const short8*)(w0b + g * 24576 + kt * 512);
                acc[g][0] = __builtin_amdgcn_mfma_f32_16x16x32_bf16(af0[0][kt], bfr, acc[g][0], 0, 0, 0);
                acc[g][1] = __builtin_amdgcn_mfma_f32_16x16x32_bf16(af0[1][kt], bfr, acc[g][1], 0, 0, 0);
            }
        }
        __syncthreads();  // b2: all a0 reads done before gate0 overwrites h0

        // ---------- gates layer 0 (in-register) ----------
        #pragma unroll
        for (int mt = 0; mt < 2; ++mt) {
            #pragma unroll
            for (int r = 0; r < 4; ++r) {
                float zi = acc[0][mt][r] + bi0;
                float zf = acc[1][mt][r] + bff0;
                float zg = acc[2][mt][r] + bg0;
                float zo = acc[3][mt][r] + bo0;
                float c  = fsig(zf) * c0s[mt][r] + fsig(zi) * ftanh_(zg);
                c0s[mt][r] = c;
                float h  = fsig(zo) * ftanh_(c);
                short hb = f2bf(h);
                int row = mt * 16 + quad * 4 + r;
                a0[row * K0P + 64 + hu] = hb;   // next-step layer0 recurrent input
                a1[row * K1P + hu]      = hb;   // layer1 input
            }
        }
        __syncthreads();  // b3: a1 h0 ready

        // ---------- layer 1: z1 = [h0;h1] @ [Wk1;Wr1] ----------
        short8 af1[2][8];
        #pragma unroll
        for (int mt = 0; mt < 2; ++mt)
            #pragma unroll
            for (int kt = 0; kt < 8; ++kt)
                af1[mt][kt] = *(const short8*)&a1[(mt * 16 + l15) * K1P + kt * 32 + quad * 8];

        #pragma unroll
        for (int g = 0; g < 4; ++g)
            #pragma unroll
            for (int mt = 0; mt < 2; ++mt)
                acc[g][mt] = (floatx4){0.f, 0.f, 0.f, 0.f};

        #pragma unroll
        for (int g = 0; g < 4; ++g) {
            #pragma unroll
            for (int kt = 0; kt < 8; ++kt) {
                short8 bfr = *(const short8*)(w1b + g * 32768 + kt * 512);
                acc[g][0] = __builtin_amdgcn_mfma_f32_16x16x32_bf16(af1[0][kt], bfr, acc[g][0], 0, 0, 0);
                acc[g][1] = __builtin_amdgcn_mfma_f32_16x16x32_bf16(af1[1][kt], bfr, acc[g][1], 0, 0, 0);
            }
        }
        __syncthreads();  // b4: all a1 reads done before gate1 overwrites h1

        // ---------- gates layer 1 (in-register) ----------
        #pragma unroll
        for (int mt = 0; mt < 2; ++mt) {
            #pragma unroll
            for (int r = 0; r < 4; ++r) {
                float zi = acc[0][mt][r] + bi1;
                float zf = acc[1][mt][r] + bff1;
                float zg = acc[2][mt][r] + bg1;
                float zo = acc[3][mt][r] + bo1;
                float c  = fsig(zf) * c1s[mt][r] + fsig(zi) * ftanh_(zg);
                c1s[mt][r] = c;
                float h  = fsig(zo) * ftanh_(c);
                int row = mt * 16 + quad * 4 + r;
                a1[row * K1P + 128 + hu] = f2bf(h);
            }
        }

        // ---------- dense head (step 49 -> s=0, ..., step 148 -> s=99) ----------
        if (step >= Tt - 1) {
            __syncthreads();  // b5: h1 visible to all waves
            floatx4 accd = (floatx4){0.f, 0.f, 0.f, 0.f};
            #pragma unroll
            for (int kt = 0; kt < 4; ++kt) {
                short8 a_ = *(const short8*)&a1[(dmt * 16 + l15) * K1P + 128 + kt * 32 + quad * 8];
                short8 b_ = *(const short8*)(wdb + kt * 512);
                accd = __builtin_amdgcn_mfma_f32_16x16x32_bf16(a_, b_, accd, 0, 0, 0);
            }
            int s = step - (Tt - 1);
            #pragma unroll
            for (int r = 0; r < 4; ++r) {
                float p = accd[r] + bdv;
                int row = dmt * 16 + quad * 4 + r;
                int col = dnt * 16 + l15;
                out[(size_t)(row0 + row) * (NOUT * Dd) + s * Dd + col] = p;  // fp32 output
                a0[row * K0P + col] = f2bf(p);   // next step's AR input (bf16 for MFMA)
            }
        }
    }
}

extern "C" void kernel_launch(void* const* d_in, const int* in_sizes, int n_in,
                              void* d_out, int out_size, void* d_ws, size_t ws_size,
                              hipStream_t stream)
{
    (void)in_sizes; (void)n_in; (void)out_size; (void)ws_size;
    prep_kernel<<<933, 256, 0, stream>>>(
        (const float*)d_in[1], (const float*)d_in[2], (const float*)d_in[3],
        (const float*)d_in[4], (const float*)d_in[5], (const float*)d_in[6],
        (const float*)d_in[7], (const float*)d_in[8], (char*)d_ws);
    lstm_kernel<<<128, 512, 0, stream>>>(
        (const float*)d_in[0], (const char*)d_ws, (float*)d_out);
}

// Round 5
// 542.760 us; speedup vs baseline: 3.1988x; 3.1988x over previous
//
#include <hip/hip_runtime.h>
#include <hip/hip_bf16.h>

// Problem constants
#define Tt   50
#define Dd   64
#define NOUT 100
#define G4   512   // 4*H
#define K0P  200   // padded LDS stride for layer0 A (192 + 8)
#define K1P  264   // padded LDS stride for layer1 A (256 + 8)
#define BM   16    // batch rows per workgroup (grid 256 = 4096/16)

typedef __attribute__((ext_vector_type(8))) short  short8;
typedef __attribute__((ext_vector_type(4))) float  floatx4;

__device__ __forceinline__ float fsig(float v)  { return __builtin_amdgcn_rcpf(1.0f + __expf(-v)); }
__device__ __forceinline__ float ftanh_(float v) { return 2.0f * __builtin_amdgcn_rcpf(1.0f + __expf(-2.0f * v)) - 1.0f; }
__device__ __forceinline__ short f2bf(float f) {
    __hip_bfloat16 h = __float2bfloat16(f);
    return *reinterpret_cast<const short*>(&h);
}

// ws layout (bytes) — unchanged from round 3:
//  w0f bf16[ 98304] @ 0        (layer0 [Wk0;Wr0] 192x512, frag order f=nt*6+kt, nt=w+8g)
//  w1f bf16[131072] @ 196608   (layer1 [Wk1;Wr1] 256x512, frag order f=nt*8+kt)
//  wdf bf16[  8192] @ 458752   (Wd 128x64, frag order f=nt*4+kt)
//  b0f f32[512]     @ 475136
//  b1f f32[512]     @ 477184
//  bdf f32[64]      @ 479232
#define W1F_OFF 196608
#define WDF_OFF 458752
#define B0F_OFF 475136
#define B1F_OFF 477184
#define BDF_OFF 479232

__global__ __launch_bounds__(256) void prep_kernel(
    const float* __restrict__ Wk0, const float* __restrict__ Wr0, const float* __restrict__ b0,
    const float* __restrict__ Wk1, const float* __restrict__ Wr1, const float* __restrict__ b1,
    const float* __restrict__ Wd,  const float* __restrict__ bd,  char* __restrict__ ws)
{
    int idx = blockIdx.x * 256 + threadIdx.x;
    short* w0f = (short*)ws;
    short* w1f = (short*)(ws + W1F_OFF);
    short* wdf = (short*)(ws + WDF_OFF);
    float* b0f = (float*)(ws + B0F_OFF);
    float* b1f = (float*)(ws + B1F_OFF);
    float* bdf = (float*)(ws + BDF_OFF);

    if (idx < 98304) {
        int f = idx >> 9, r = idx & 511;
        int lane = r >> 3, j = r & 7;
        int nt = f / 6, kt = f - nt * 6;
        int k = kt * 32 + (lane >> 4) * 8 + j;
        int col = nt * 16 + (lane & 15);
        w0f[idx] = f2bf((k < Dd) ? Wk0[k * G4 + col] : Wr0[(k - Dd) * G4 + col]);
    } else if (idx < 229376) {
        int i2 = idx - 98304;
        int f = i2 >> 9, r = i2 & 511;
        int lane = r >> 3, j = r & 7;
        int nt = f >> 3, kt = f & 7;
        int k = kt * 32 + (lane >> 4) * 8 + j;
        int col = nt * 16 + (lane & 15);
        w1f[i2] = f2bf((k < 128) ? Wk1[k * G4 + col] : Wr1[(k - 128) * G4 + col]);
    } else if (idx < 237568) {
        int i2 = idx - 229376;
        int f = i2 >> 9, r = i2 & 511;
        int lane = r >> 3, j = r & 7;
        int nt = f >> 2, kt = f & 3;
        int k = kt * 32 + (lane >> 4) * 8 + j;
        int col = nt * 16 + (lane & 15);
        wdf[i2] = f2bf(Wd[k * Dd + col]);
    } else if (idx < 237568 + 1088) {
        int i2 = idx - 237568;
        if (i2 < 512)       b0f[i2]        = b0[i2];
        else if (i2 < 1024) b1f[i2 - 512]  = b1[i2 - 512];
        else                bdf[i2 - 1024] = bd[i2 - 1024];
    }
}

// Dynamic LDS layout (bytes) — FIXED round-4 overflow (wdl is 16384 B, not 8192):
//  a0   @ 0       : 16*200*2 = 6400   (layer0 A: x/pred | h0)
//  a1   @ 6400    : 16*264*2 = 8448   (layer1 A: h0 | h1)
//  wdl  @ 14848   : 8192 shorts = 16384 B (dense weights, all 16 frag-sets)
//  w0l  @ 31232   : 131072            (W0 pairs p=0..15, [p][wave][512])
//  total 162304 (158.5 KiB <= 160 KiB)
#define SM_A1  6400
#define SM_WD  14848
#define SM_W0  31232
#define SM_TOT 162304

// grid 256, block 512 (8 waves), 1 block/CU. Wave w owns hidden cols 16w..16w+15
// for all 4 gates. ALL weights CU-resident: W1+8 W0-pairs in registers,
// 16 W0-pairs + Wd in LDS. Zero global weight traffic in the step loop.
__global__ __launch_bounds__(512, 2) void lstm_kernel(
    const float* __restrict__ x, const char* __restrict__ ws, float* __restrict__ out)
{
    extern __shared__ char smem[];
    short* a0  = (short*)smem;
    short* a1  = (short*)(smem + SM_A1);
    short* wdl = (short*)(smem + SM_WD);
    short* w0l = (short*)(smem + SM_W0);

    const short* w0f = (const short*)ws;
    const short* w1f = (const short*)(ws + W1F_OFF);
    const short* wdf = (const short*)(ws + WDF_OFF);
    const float* b0f = (const float*)(ws + B0F_OFF);
    const float* b1f = (const float*)(ws + B1F_OFF);
    const float* bdf = (const float*)(ws + BDF_OFF);

    const int tid  = threadIdx.x;
    const int w    = tid >> 6;        // wave 0..7
    const int lane = tid & 63;
    const int l15  = lane & 15;
    const int quad = lane >> 4;
    const int row0 = blockIdx.x * BM;

    // ---- one-time staging ----
    for (int i = tid; i < BM * K0P; i += 512) a0[i] = 0;
    for (int i = tid; i < BM * K1P; i += 512) a1[i] = 0;
    for (int i = tid; i < 8192; i += 512) wdl[i] = wdf[i];
    // W0 pairs p<16 -> LDS, dst [(p*8+wv)*512 + e], src f=(8g+wv)*6+kt
    for (int c = tid; c < 8192; c += 512) {      // short8 chunks
        int e8 = c & 63;                          // 64 chunks per (p,wv)
        int wv = (c >> 6) & 7;
        int p  = c >> 9;                          // 0..15
        int g = p / 6, kt = p - g * 6;
        const short* src = w0f + ((((g * 8 + wv) * 6) + kt) << 9) + e8 * 8;
        *(short8*)&w0l[((p * 8 + wv) << 9) + e8 * 8] = *(const short8*)src;
    }

    // register-resident weights
    const short* w0b = w0f + w * 3072 + lane * 8;   // + g*24576 + kt*512
    const short* w1b = w1f + w * 4096 + lane * 8;   // + g*32768 + kt*512
    short8 W1R[4][8];
    #pragma unroll
    for (int g = 0; g < 4; ++g)
        #pragma unroll
        for (int kt = 0; kt < 8; ++kt)
            W1R[g][kt] = *(const short8*)(w1b + g * 32768 + kt * 512);
    short8 W0R[8];   // pairs p = 16..23  (g*6+kt >= 16)
    #pragma unroll
    for (int p = 16; p < 24; ++p) {
        int g = p / 6, kt = p - g * 6;
        W0R[p - 16] = *(const short8*)(w0b + g * 24576 + kt * 512);
    }

    const int hu = w * 16 + l15;
    const float bi0 = b0f[hu], bff0 = b0f[128 + hu], bg0 = b0f[256 + hu], bo0 = b0f[384 + hu];
    const float bi1 = b1f[hu], bff1 = b1f[128 + hu], bg1 = b1f[256 + hu], bo1 = b1f[384 + hu];
    const float bdv = bdf[(w & 3) * 16 + l15];

    float c0s[4] = {0.f, 0.f, 0.f, 0.f};
    float c1s[4] = {0.f, 0.f, 0.f, 0.f};

    __syncthreads();   // staging complete

    for (int step = 0; step < 149; ++step) {
        if (step < Tt) {
            // stage x[:, step, :] -> a0 cols 0..63 (fp32 -> bf16)
            int colx = tid & 63, rg = tid >> 6;
            #pragma unroll
            for (int kk = 0; kk < 2; ++kk) {
                int r = rg + 8 * kk;
                a0[r * K0P + colx] = f2bf(x[(size_t)(row0 + r) * (Tt * Dd) + step * Dd + colx]);
            }
        }
        __syncthreads();  // b1: a0 (x/pred, h0) ready

        // ---------- layer 0: z0 = [x;h0] @ [Wk0;Wr0] ----------
        floatx4 acc[4];
        #pragma unroll
        for (int g = 0; g < 4; ++g) acc[g] = (floatx4){0.f, 0.f, 0.f, 0.f};

        #pragma unroll
        for (int kt = 0; kt < 6; ++kt) {
            short8 af = *(const short8*)&a0[l15 * K0P + kt * 32 + quad * 8];
            #pragma unroll
            for (int g = 0; g < 4; ++g) {
                int p = g * 6 + kt;
                short8 bfr = (p < 16) ? *(const short8*)&w0l[((p * 8 + w) << 9) + lane * 8]
                                      : W0R[p - 16];
                acc[g] = __builtin_amdgcn_mfma_f32_16x16x32_bf16(af, bfr, acc[g], 0, 0, 0);
            }
        }
        __syncthreads();  // b2: a0 reads done before h0 overwrite

        // ---------- gates layer 0 ----------
        #pragma unroll
        for (int r = 0; r < 4; ++r) {
            float zi = acc[0][r] + bi0;
            float zf = acc[1][r] + bff0;
            float zg = acc[2][r] + bg0;
            float zo = acc[3][r] + bo0;
            float c  = fsig(zf) * c0s[r] + fsig(zi) * ftanh_(zg);
            c0s[r] = c;
            float h  = fsig(zo) * ftanh_(c);
            short hb = f2bf(h);
            int row = quad * 4 + r;
            a0[row * K0P + 64 + hu] = hb;
            a1[row * K1P + hu]      = hb;
        }
        __syncthreads();  // b3: a1 h0 ready

        // ---------- layer 1: z1 = [h0;h1] @ [Wk1;Wr1] ----------
        #pragma unroll
        for (int g = 0; g < 4; ++g) acc[g] = (floatx4){0.f, 0.f, 0.f, 0.f};

        #pragma unroll
        for (int kt = 0; kt < 8; ++kt) {
            short8 af = *(const short8*)&a1[l15 * K1P + kt * 32 + quad * 8];
            #pragma unroll
            for (int g = 0; g < 4; ++g)
                acc[g] = __builtin_amdgcn_mfma_f32_16x16x32_bf16(af, W1R[g][kt], acc[g], 0, 0, 0);
        }
        __syncthreads();  // b4: a1 reads done before h1 overwrite

        // ---------- gates layer 1 ----------
        #pragma unroll
        for (int r = 0; r < 4; ++r) {
            float zi = acc[0][r] + bi1;
            float zf = acc[1][r] + bff1;
            float zg = acc[2][r] + bg1;
            float zo = acc[3][r] + bo1;
            float c  = fsig(zf) * c1s[r] + fsig(zi) * ftanh_(zg);
            c1s[r] = c;
            float h  = fsig(zo) * ftanh_(c);
            int row = quad * 4 + r;
            a1[row * K1P + 128 + hu] = f2bf(h);
        }

        // ---------- dense head (waves 0..3) ----------
        if (step >= Tt - 1) {
            __syncthreads();  // b5: h1 visible
            if (w < 4) {
                floatx4 ad = (floatx4){0.f, 0.f, 0.f, 0.f};
                #pragma unroll
                for (int kt = 0; kt < 4; ++kt) {
                    short8 a_ = *(const short8*)&a1[l15 * K1P + 128 + kt * 32 + quad * 8];
                    short8 b_ = *(const short8*)&wdl[((w * 4 + kt) << 9) + lane * 8];
                    ad = __builtin_amdgcn_mfma_f32_16x16x32_bf16(a_, b_, ad, 0, 0, 0);
                }
                int s = step - (Tt - 1);
                #pragma unroll
                for (int r = 0; r < 4; ++r) {
                    float p = ad[r] + bdv;
                    int row = quad * 4 + r;
                    int col = w * 16 + l15;
                    out[(size_t)(row0 + row) * (NOUT * Dd) + s * Dd + col] = p;
                    a0[row * K0P + col] = f2bf(p);   // AR feedback
                }
            }
        }
    }
}

extern "C" void kernel_launch(void* const* d_in, const int* in_sizes, int n_in,
                              void* d_out, int out_size, void* d_ws, size_t ws_size,
                              hipStream_t stream)
{
    (void)in_sizes; (void)n_in; (void)out_size; (void)ws_size;
    static_assert(SM_TOT <= 160 * 1024, "LDS budget");
    hipFuncSetAttribute(reinterpret_cast<const void*>(lstm_kernel),
                        hipFuncAttributeMaxDynamicSharedMemorySize, SM_TOT);
    prep_kernel<<<933, 256, 0, stream>>>(
        (const float*)d_in[1], (const float*)d_in[2], (const float*)d_in[3],
        (const float*)d_in[4], (const float*)d_in[5], (const float*)d_in[6],
        (const float*)d_in[7], (const float*)d_in[8], (char*)d_ws);
    lstm_kernel<<<256, 512, SM_TOT, stream>>>(
        (const float*)d_in[0], (const char*)d_ws, (float*)d_out);
}

// Round 6
// 505.865 us; speedup vs baseline: 3.4321x; 1.0729x over previous
//
#include <hip/hip_runtime.h>
#include <hip/hip_bf16.h>

// Problem constants
#define Tt   50
#define Dd   64
#define NOUT 100
#define G4   512   // 4*H
#define K0S  72    // a0 LDS stride (64 x-cols + 8 pad)
#define K1P  264   // a1 LDS stride (256 + 8 pad)
#define BM   16    // batch rows per workgroup (grid 256 = 4096/16)

typedef __attribute__((ext_vector_type(8))) short  short8;
typedef __attribute__((ext_vector_type(4))) float  floatx4;

#if __has_builtin(__builtin_amdgcn_exp2f)
#define EXP2(v) __builtin_amdgcn_exp2f(v)
#else
#define EXP2(v) exp2f(v)
#endif
__device__ __forceinline__ float rcp_(float v) { return __builtin_amdgcn_rcpf(v); }
// args pre-scaled by -log2e (sigmoid) / -2log2e (tanh) via weight/bias prescale
__device__ __forceinline__ float fsig2(float u)  { return rcp_(1.0f + EXP2(u)); }
__device__ __forceinline__ float ftanh2(float u) { return fmaf(2.0f, rcp_(1.0f + EXP2(u)), -1.0f); }
#define KN2L2E (-2.8853900817779268f)   // -2*log2(e), for tanh(c) with natural-units c

__device__ __forceinline__ short f2bf(float f) {
    __hip_bfloat16 h = __float2bfloat16(f);
    return *reinterpret_cast<const short*>(&h);
}

// ws layout (bytes):
//  w0f bf16[ 98304] @ 0        (layer0 [Wk0;Wr0] 192x512, frag order f=nt*6+kt, nt=w+8g, PRESCALED)
//  w1f bf16[131072] @ 196608   (layer1 [Wk1;Wr1] 256x512, frag order f=nt*8+kt, PRESCALED)
//  wdf bf16[  8192] @ 458752   (Wd 128x64, frag order f=nt*4+kt, unscaled)
//  b0f f32[512]     @ 475136   (PRESCALED)
//  b1f f32[512]     @ 477184   (PRESCALED)
//  bdf f32[64]      @ 479232   (unscaled)
#define W1F_OFF 196608
#define WDF_OFF 458752
#define B0F_OFF 475136
#define B1F_OFF 477184
#define BDF_OFF 479232

__global__ __launch_bounds__(256) void prep_kernel(
    const float* __restrict__ Wk0, const float* __restrict__ Wr0, const float* __restrict__ b0,
    const float* __restrict__ Wk1, const float* __restrict__ Wr1, const float* __restrict__ b1,
    const float* __restrict__ Wd,  const float* __restrict__ bd,  char* __restrict__ ws)
{
    int idx = blockIdx.x * 256 + threadIdx.x;
    short* w0f = (short*)ws;
    short* w1f = (short*)(ws + W1F_OFF);
    short* wdf = (short*)(ws + WDF_OFF);
    float* b0f = (float*)(ws + B0F_OFF);
    float* b1f = (float*)(ws + B1F_OFF);
    float* bdf = (float*)(ws + BDF_OFF);
    const float NL2E = -1.4426950408889634f;   // -log2(e): i,f,o (sigmoid)
    const float N2L2E = -2.8853900817779268f;  // -2log2(e): g (tanh)

    if (idx < 98304) {
        int f = idx >> 9, r = idx & 511;
        int lane = r >> 3, j = r & 7;
        int nt = f / 6, kt = f - nt * 6;
        int k = kt * 32 + (lane >> 4) * 8 + j;
        int col = nt * 16 + (lane & 15);
        float sc = ((col >> 7) == 2) ? N2L2E : NL2E;
        w0f[idx] = f2bf(sc * ((k < Dd) ? Wk0[k * G4 + col] : Wr0[(k - Dd) * G4 + col]));
    } else if (idx < 229376) {
        int i2 = idx - 98304;
        int f = i2 >> 9, r = i2 & 511;
        int lane = r >> 3, j = r & 7;
        int nt = f >> 3, kt = f & 7;
        int k = kt * 32 + (lane >> 4) * 8 + j;
        int col = nt * 16 + (lane & 15);
        float sc = ((col >> 7) == 2) ? N2L2E : NL2E;
        w1f[i2] = f2bf(sc * ((k < 128) ? Wk1[k * G4 + col] : Wr1[(k - 128) * G4 + col]));
    } else if (idx < 237568) {
        int i2 = idx - 229376;
        int f = i2 >> 9, r = i2 & 511;
        int lane = r >> 3, j = r & 7;
        int nt = f >> 2, kt = f & 3;
        int k = kt * 32 + (lane >> 4) * 8 + j;
        int col = nt * 16 + (lane & 15);
        wdf[i2] = f2bf(Wd[k * Dd + col]);
    } else if (idx < 237568 + 1088) {
        int i2 = idx - 237568;
        if (i2 < 512) {
            float sc = ((i2 >> 7) == 2) ? N2L2E : NL2E;
            b0f[i2] = sc * b0[i2];
        } else if (i2 < 1024) {
            int c = i2 - 512;
            float sc = ((c >> 7) == 2) ? N2L2E : NL2E;
            b1f[c] = sc * b1[c];
        } else bdf[i2 - 1024] = bd[i2 - 1024];
    }
}

// Dynamic LDS layout (bytes):
//  a0[2] @ 0     : 2 × 16*72*2  = 4608   (x/pred tiles, ping-pong by step parity)
//  a1[2] @ 4608  : 2 × 16*264*2 = 16896  (h0 | h1 tiles, ping-pong)
//  w0l   @ 21504 : 131072                (W0 pairs p=0..15, [p][wave][512])
//  total 152576 (149 KiB)
#define SM_A1  4608
#define SM_W0  21504
#define SM_TOT 152576
#define A0SZ   1152   // shorts per a0 buffer
#define A1SZ   4224   // shorts per a1 buffer

// grid 256, block 512 (8 waves), 1 block/CU. Wave w owns hidden cols 16w..16w+15.
// All weights CU-resident. Double-buffered activations -> 1 barrier/warm step,
// 3/AR step (was 5). Gates feed v_exp directly via -log2e prescale; biases are
// folded into the MFMA C-operand init.
__global__ __launch_bounds__(512, 2) void lstm_kernel(
    const float* __restrict__ x, const char* __restrict__ ws, float* __restrict__ out)
{
    extern __shared__ char smem[];
    short* a0b = (short*)smem;                 // 2 buffers of A0SZ
    short* a1b = (short*)(smem + SM_A1);       // 2 buffers of A1SZ
    short* w0l = (short*)(smem + SM_W0);

    const short* w0f = (const short*)ws;
    const short* w1f = (const short*)(ws + W1F_OFF);
    const short* wdf = (const short*)(ws + WDF_OFF);
    const float* b0f = (const float*)(ws + B0F_OFF);
    const float* b1f = (const float*)(ws + B1F_OFF);
    const float* bdf = (const float*)(ws + BDF_OFF);

    const int tid  = threadIdx.x;
    const int w    = tid >> 6;        // wave 0..7
    const int lane = tid & 63;
    const int l15  = lane & 15;
    const int quad = lane >> 4;
    const int row0 = blockIdx.x * BM;

    // ---- one-time staging ----
    for (int i = tid; i < 2 * A0SZ; i += 512) a0b[i] = 0;
    for (int i = tid; i < 2 * A1SZ; i += 512) a1b[i] = 0;
    // W0 pairs p<16 -> LDS
    for (int c = tid; c < 8192; c += 512) {       // short8 chunks
        int e8 = c & 63;
        int wv = (c >> 6) & 7;
        int p  = c >> 9;                           // 0..15
        int g = p / 6, kt = p - g * 6;
        const short* src = w0f + ((((g * 8 + wv) * 6) + kt) << 9) + e8 * 8;
        *(short8*)&w0l[((p * 8 + wv) << 9) + e8 * 8] = *(const short8*)src;
    }
    {   // stage x_0 -> a0[0]
        int colx = tid & 63, rg = tid >> 6;
        a0b[rg * K0S + colx]       = f2bf(x[(size_t)(row0 + rg) * (Tt * Dd) + colx]);
        a0b[(rg + 8) * K0S + colx] = f2bf(x[(size_t)(row0 + rg + 8) * (Tt * Dd) + colx]);
    }

    // register-resident weights
    const short* w0rb = w0f + w * 3072 + lane * 8;
    const short* w1rb = w1f + w * 4096 + lane * 8;
    short8 W1R[4][8];
    #pragma unroll
    for (int g = 0; g < 4; ++g)
        #pragma unroll
        for (int kt = 0; kt < 8; ++kt)
            W1R[g][kt] = *(const short8*)(w1rb + g * 32768 + kt * 512);
    short8 W0R[8];   // pairs p = 16..23
    #pragma unroll
    for (int p = 16; p < 24; ++p) {
        int g = p / 6, kt = p - g * 6;
        W0R[p - 16] = *(const short8*)(w0rb + g * 24576 + kt * 512);
    }
    short8 WdR[4];
    if (w < 4) {
        #pragma unroll
        for (int kt = 0; kt < 4; ++kt)
            WdR[kt] = *(const short8*)(wdf + ((w * 4 + kt) << 9) + lane * 8);
    }

    const int hu = w * 16 + l15;
    const float bi0 = b0f[hu], bff0 = b0f[128 + hu], bg0 = b0f[256 + hu], bo0 = b0f[384 + hu];
    const float bi1 = b1f[hu], bff1 = b1f[128 + hu], bg1 = b1f[256 + hu], bo1 = b1f[384 + hu];
    const float bdv = bdf[(w & 3) * 16 + l15];

    float c0s[4] = {0.f, 0.f, 0.f, 0.f};
    float c1s[4] = {0.f, 0.f, 0.f, 0.f};

    const int colx = tid & 63, rg = tid >> 6;

    __syncthreads();   // staging complete

    for (int step = 0; step < 149; ++step) {
        const int p = step & 1, q = p ^ 1;
        short* a0p = a0b + p * A0SZ;  short* a0q = a0b + q * A0SZ;
        short* a1p = a1b + p * A1SZ;  short* a1q = a1b + q * A1SZ;

        // issue next-x global loads early (consumed at step bottom)
        float xv0, xv1;
        if (step < Tt - 1) {
            xv0 = x[(size_t)(row0 + rg)     * (Tt * Dd) + (step + 1) * Dd + colx];
            xv1 = x[(size_t)(row0 + rg + 8) * (Tt * Dd) + (step + 1) * Dd + colx];
        }

        // ---------- layer 0: A = [x|h0], x from a0[p], h0 from a1[q] ----------
        floatx4 acc[4];
        acc[0] = (floatx4){bi0,  bi0,  bi0,  bi0};
        acc[1] = (floatx4){bff0, bff0, bff0, bff0};
        acc[2] = (floatx4){bg0,  bg0,  bg0,  bg0};
        acc[3] = (floatx4){bo0,  bo0,  bo0,  bo0};

        #pragma unroll
        for (int kt = 0; kt < 6; ++kt) {
            short8 af = (kt < 2)
                ? *(const short8*)&a0p[l15 * K0S + kt * 32 + quad * 8]
                : *(const short8*)&a1q[l15 * K1P + (kt - 2) * 32 + quad * 8];
            #pragma unroll
            for (int g = 0; g < 4; ++g) {
                int pp = g * 6 + kt;
                short8 bfr = (pp < 16) ? *(const short8*)&w0l[((pp * 8 + w) << 9) + lane * 8]
                                       : W0R[pp - 16];
                acc[g] = __builtin_amdgcn_mfma_f32_16x16x32_bf16(af, bfr, acc[g], 0, 0, 0);
            }
        }

        // ---------- gates layer 0 -> h0' into a1[p] cols 0..127 ----------
        #pragma unroll
        for (int r = 0; r < 4; ++r) {
            float si = fsig2(acc[0][r]);
            float sf = fsig2(acc[1][r]);
            float tg = ftanh2(acc[2][r]);
            float so = fsig2(acc[3][r]);
            float c  = fmaf(sf, c0s[r], si * tg);
            c0s[r] = c;
            float h  = so * ftanh2(c * KN2L2E);
            a1p[(quad * 4 + r) * K1P + hu] = f2bf(h);
        }

        // stage next x into a0[q] (before the barrier that publishes it)
        if (step < Tt - 1) {
            a0q[rg * K0S + colx]       = f2bf(xv0);
            a0q[(rg + 8) * K0S + colx] = f2bf(xv1);
        }
        __syncthreads();   // C: h0' (and next-x) visible

        // ---------- layer 1: A = a1[p] (h0' | h1) ----------
        acc[0] = (floatx4){bi1,  bi1,  bi1,  bi1};
        acc[1] = (floatx4){bff1, bff1, bff1, bff1};
        acc[2] = (floatx4){bg1,  bg1,  bg1,  bg1};
        acc[3] = (floatx4){bo1,  bo1,  bo1,  bo1};

        #pragma unroll
        for (int kt = 0; kt < 8; ++kt) {
            short8 af = *(const short8*)&a1p[l15 * K1P + kt * 32 + quad * 8];
            #pragma unroll
            for (int g = 0; g < 4; ++g)
                acc[g] = __builtin_amdgcn_mfma_f32_16x16x32_bf16(af, W1R[g][kt], acc[g], 0, 0, 0);
        }

        // ---------- gates layer 1 -> h1' into a1[q] cols 128..255 ----------
        #pragma unroll
        for (int r = 0; r < 4; ++r) {
            float si = fsig2(acc[0][r]);
            float sf = fsig2(acc[1][r]);
            float tg = ftanh2(acc[2][r]);
            float so = fsig2(acc[3][r]);
            float c  = fmaf(sf, c1s[r], si * tg);
            c1s[r] = c;
            float h  = so * ftanh2(c * KN2L2E);
            a1q[(quad * 4 + r) * K1P + 128 + hu] = f2bf(h);
        }

        // ---------- dense head (steps >= 49): pred = h1' @ Wd + bd ----------
        if (step >= Tt - 1) {
            __syncthreads();   // D: h1' visible
            if (w < 4) {
                floatx4 ad = (floatx4){bdv, bdv, bdv, bdv};
                #pragma unroll
                for (int kt = 0; kt < 4; ++kt) {
                    short8 a_ = *(const short8*)&a1q[l15 * K1P + 128 + kt * 32 + quad * 8];
                    ad = __builtin_amdgcn_mfma_f32_16x16x32_bf16(a_, WdR[kt], ad, 0, 0, 0);
                }
                int s = step - (Tt - 1);
                #pragma unroll
                for (int r = 0; r < 4; ++r) {
                    float pv = ad[r];
                    int row = quad * 4 + r;
                    int col = w * 16 + l15;
                    out[(size_t)(row0 + row) * (NOUT * Dd) + s * Dd + col] = pv;
                    a0q[row * K0S + col] = f2bf(pv);   // AR feedback for step+1
                }
            }
            __syncthreads();   // publish pred before next step's L0 reads a0[q]
        }
    }
}

extern "C" void kernel_launch(void* const* d_in, const int* in_sizes, int n_in,
                              void* d_out, int out_size, void* d_ws, size_t ws_size,
                              hipStream_t stream)
{
    (void)in_sizes; (void)n_in; (void)out_size; (void)ws_size;
    static_assert(SM_TOT <= 160 * 1024, "LDS budget");
    hipFuncSetAttribute(reinterpret_cast<const void*>(lstm_kernel),
                        hipFuncAttributeMaxDynamicSharedMemorySize, SM_TOT);
    prep_kernel<<<933, 256, 0, stream>>>(
        (const float*)d_in[1], (const float*)d_in[2], (const float*)d_in[3],
        (const float*)d_in[4], (const float*)d_in[5], (const float*)d_in[6],
        (const float*)d_in[7], (const float*)d_in[8], (char*)d_ws);
    lstm_kernel<<<256, 512, SM_TOT, stream>>>(
        (const float*)d_in[0], (const char*)d_ws, (float*)d_out);
}